// Round 1
// baseline (5281.179 us; speedup 1.0000x reference)
//
#include <hip/hip_runtime.h>

#define EDGE_DIM 64
#define ADDED    24
#define H_DIM    256
#define OUT_DIM  256

// ---------------------------------------------------------------------------
// Edge stage: m[e] = edge_feat[e] @ W_msg + b_msg ; atomic scatter-sum to ah.
// One thread per edge. W_msg/b_msg indices are wave-uniform -> compiler emits
// s_load (scalar pipe), FMA stream is v_fmac v,s,v.
// ---------------------------------------------------------------------------
__global__ __launch_bounds__(256) void edge_scatter_kernel(
    const float* __restrict__ ef, const float* __restrict__ Wmsg,
    const float* __restrict__ bmsg, const int* __restrict__ dst,
    float* __restrict__ ah, int nEdges)
{
    int e = blockIdx.x * blockDim.x + threadIdx.x;
    if (e >= nEdges) return;

    const float4* ef4 = (const float4*)(ef + (size_t)e * EDGE_DIM);
    float acc[ADDED];
#pragma unroll
    for (int k = 0; k < ADDED; ++k) acc[k] = bmsg[k];

#pragma unroll
    for (int ii = 0; ii < EDGE_DIM / 4; ++ii) {
        float4 v = ef4[ii];
#pragma unroll
        for (int k = 0; k < ADDED; ++k) {
            acc[k] = fmaf(v.x, Wmsg[(4 * ii + 0) * ADDED + k], acc[k]);
            acc[k] = fmaf(v.y, Wmsg[(4 * ii + 1) * ADDED + k], acc[k]);
            acc[k] = fmaf(v.z, Wmsg[(4 * ii + 2) * ADDED + k], acc[k]);
            acc[k] = fmaf(v.w, Wmsg[(4 * ii + 3) * ADDED + k], acc[k]);
        }
    }

    float* dp = ah + (size_t)dst[e] * ADDED;
#pragma unroll
    for (int k = 0; k < ADDED; ++k) atomicAdd(dp + k, acc[k]);
}

// ---------------------------------------------------------------------------
// Node stage: out[n] = relu(concat(h[n], ah[n]*norm[n]) @ W1 + b1).
// Block = 256 threads (one output column each), NB=16 nodes per block.
// W1 column loads coalesced + reused x16; h/ah loads wave-uniform -> s_load.
// ---------------------------------------------------------------------------
#define NB 16
__global__ __launch_bounds__(256) void node_update_kernel(
    const float* __restrict__ h, const float* __restrict__ ah,
    const float* __restrict__ norm, const float* __restrict__ W1,
    const float* __restrict__ b1, float* __restrict__ out, int nNodes)
{
    int j  = threadIdx.x;
    int n0 = blockIdx.x * NB;
    if (n0 >= nNodes) return;

    float acc[NB];
    float bj = b1[j];
#pragma unroll
    for (int i = 0; i < NB; ++i) acc[i] = bj;

    if (n0 + NB <= nNodes) {
        // fast path: full tile
        const float* hb = h + (size_t)n0 * H_DIM;
#pragma unroll 4
        for (int k = 0; k < H_DIM; ++k) {
            float w = W1[k * OUT_DIM + j];
#pragma unroll
            for (int i = 0; i < NB; ++i)
                acc[i] = fmaf(hb[(size_t)i * H_DIM + k], w, acc[i]);
        }

        float wtail[ADDED];
#pragma unroll
        for (int k = 0; k < ADDED; ++k) wtail[k] = W1[(H_DIM + k) * OUT_DIM + j];
        const float* ab = ah + (size_t)n0 * ADDED;
#pragma unroll
        for (int i = 0; i < NB; ++i) {
            float a = 0.f;
#pragma unroll
            for (int k = 0; k < ADDED; ++k)
                a = fmaf(ab[i * ADDED + k], wtail[k], a);
            acc[i] = fmaf(a, norm[n0 + i], acc[i]);
        }

#pragma unroll
        for (int i = 0; i < NB; ++i)
            out[(size_t)(n0 + i) * OUT_DIM + j] = fmaxf(acc[i], 0.f);
    } else {
        // tail tile (not hit for N=100000, kept for safety)
        int cnt = nNodes - n0;
        for (int i = 0; i < cnt; ++i) {
            float a = b1[j];
            for (int k = 0; k < H_DIM; ++k)
                a = fmaf(h[(size_t)(n0 + i) * H_DIM + k], W1[k * OUT_DIM + j], a);
            float t = 0.f;
            for (int k = 0; k < ADDED; ++k)
                t = fmaf(ah[(size_t)(n0 + i) * ADDED + k], W1[(H_DIM + k) * OUT_DIM + j], t);
            a = fmaf(t, norm[n0 + i], a);
            out[(size_t)(n0 + i) * OUT_DIM + j] = fmaxf(a, 0.f);
        }
    }
}

extern "C" void kernel_launch(void* const* d_in, const int* in_sizes, int n_in,
                              void* d_out, int out_size, void* d_ws, size_t ws_size,
                              hipStream_t stream) {
    const float* h     = (const float*)d_in[0];
    const float* ef    = (const float*)d_in[1];
    const float* norm  = (const float*)d_in[2];
    const float* Wmsg  = (const float*)d_in[3];
    const float* bmsg  = (const float*)d_in[4];
    const float* W1    = (const float*)d_in[5];
    const float* b1    = (const float*)d_in[6];
    const int*   dst   = (const int*)d_in[7];
    float* out = (float*)d_out;

    int nNodes = in_sizes[0] / H_DIM;     // 100000
    int nEdges = in_sizes[1] / EDGE_DIM;  // 3200000

    float* ah = (float*)d_ws;             // [nNodes, ADDED] accumulator
    hipMemsetAsync(ah, 0, (size_t)nNodes * ADDED * sizeof(float), stream);

    int eblocks = (nEdges + 255) / 256;
    edge_scatter_kernel<<<eblocks, 256, 0, stream>>>(ef, Wmsg, bmsg, dst, ah, nEdges);

    int nblocks = (nNodes + NB - 1) / NB;
    node_update_kernel<<<nblocks, 256, 0, stream>>>(h, ah, norm, W1, b1, out, nNodes);
}